// Round 5
// baseline (151.421 us; speedup 1.0000x reference)
//
#include <hip/hip_runtime.h>
#include <cmath>

namespace {

constexpr int Dc  = 256;    // channels
constexpr int NB  = 16;     // batch
constexpr int NSP = 1024;   // H*W
constexpr int OC3 = 768;    // 3*D

typedef __attribute__((ext_vector_type(8))) short  short8;
typedef __attribute__((ext_vector_type(8))) ushort ushort8;
typedef __attribute__((ext_vector_type(4))) ushort ushort4_v;
typedef __attribute__((ext_vector_type(4))) float  f32x4;

__device__ inline ushort f2bf(float f) {
  unsigned u = __builtin_bit_cast(unsigned, f);
  unsigned r = (u + 0x7FFFu + ((u >> 16) & 1u)) >> 16;
  return (ushort)r;
}

// Barrier WITHOUT the compiler's vmcnt(0) drain (T4: prefetch loads stay in
// flight across the barrier; compiler still emits counted vmcnt before each
// ds_write of a prefetched register). lgkmcnt(0) publishes our LDS writes
// and retires our LDS reads before the rendezvous.
__device__ __forceinline__ void sync_lds() {
  __builtin_amdgcn_sched_barrier(0);
  asm volatile("s_waitcnt lgkmcnt(0)" ::: "memory");
  __builtin_amdgcn_s_barrier();
  __builtin_amdgcn_sched_barrier(0);
}

// ---------------- templated MFMA GEMM core (bf16, fp32 acc) ----------------
// C[m][n] = sum_k A[m0+m][k]*B[n0+n][k]; tile BM x 128, 4 waves, BK=32,
// distance-2 register prefetch (static reg sets), double-buffered LDS,
// XOR chunk swizzle (bank-conflict free, verified r2: SQ_LDS_BANK_CONFLICT=0).
// REQUIRES: (K/32) even.
template<int BM>
__device__ __forceinline__ void mfma_core(
    const ushort* __restrict__ Abase, int lda,
    const ushort* __restrict__ Bbase, int ldb,
    int m0, int n0, int K, f32x4 (&acc)[BM / 32][4])
{
  constexpr int MI  = BM / 32;   // m-frags per wave
  constexpr int ASL = BM / 64;   // A staging slots per thread
  __shared__ short As[2][BM * 32];
  __shared__ short Bs[2][128 * 32];
  const int t = threadIdx.x;
  const int lane = t & 63, wid = t >> 6;
  const int wm = (wid >> 1) * (BM / 2);
  const int wo = (wid & 1) * 64;
  const int lm = lane & 15, lk = lane >> 4;
  const int aph = lk ^ ((lm >> 1) & 3);

  const int row0 = t >> 2, chunk = t & 3;
  const int phys = chunk ^ ((row0 >> 1) & 3);
  const int st0 = row0 * 32 + phys * 8;

  const ushort* Ap = Abase + (size_t)(m0 + row0) * lda + chunk * 8;
  const ushort* Bp = Bbase + (size_t)(n0 + row0) * ldb + chunk * 8;
  const size_t lda64 = (size_t)64 * lda;
  const size_t ldb64 = (size_t)64 * ldb;
  const int niter = K >> 5;

  short8 a0[ASL], a1[ASL], b0[2], b1[2];
#pragma unroll
  for (int i = 0; i < ASL; ++i) {
    a0[i] = *(const short8*)(Ap + i * lda64);
    a1[i] = *(const short8*)(Ap + i * lda64 + 32);
  }
  b0[0] = *(const short8*)(Bp);
  b0[1] = *(const short8*)(Bp + ldb64);
  b1[0] = *(const short8*)(Bp + 32);
  b1[1] = *(const short8*)(Bp + ldb64 + 32);

  auto step = [&](int kk, int buf, short8 (&ar)[ASL], short8 (&br)[2]) {
    short* Ab = &As[buf][0];
    short* Bb = &Bs[buf][0];
#pragma unroll
    for (int i = 0; i < ASL; ++i) *(short8*)&Ab[st0 + i * 2048] = ar[i];
    *(short8*)&Bb[st0] = br[0];
    *(short8*)&Bb[st0 + 2048] = br[1];
    if (kk + 2 < niter) {
      const int c0 = (kk + 2) << 5;
#pragma unroll
      for (int i = 0; i < ASL; ++i)
        ar[i] = *(const short8*)(Ap + i * lda64 + c0);
      br[0] = *(const short8*)(Bp + c0);
      br[1] = *(const short8*)(Bp + ldb64 + c0);
    }
    sync_lds();
    short8 af[MI], bw[4];
#pragma unroll
    for (int mi = 0; mi < MI; ++mi)
      af[mi] = *(const short8*)&Ab[(wm + mi * 16 + lm) * 32 + aph * 8];
#pragma unroll
    for (int oi = 0; oi < 4; ++oi)
      bw[oi] = *(const short8*)&Bb[(wo + oi * 16 + lm) * 32 + aph * 8];
#pragma unroll
    for (int mi = 0; mi < MI; ++mi)
#pragma unroll
      for (int oi = 0; oi < 4; ++oi)
        acc[mi][oi] = __builtin_amdgcn_mfma_f32_16x16x32_bf16(
            af[mi], bw[oi], acc[mi][oi], 0, 0, 0);
    // reads of this buffer are retired at the next sync_lds (lgkmcnt(0))
    // before its next overwrite two iterations later.
  };

  for (int kk = 0; kk < niter; kk += 2) {
    step(kk, 0, a0, b0);
    step(kk + 1, 1, a1, b1);
  }
}

// ---------------- K0w: wb[o][c] = bf16(w_qkv[o][c])
__global__ __launch_bounds__(256) void k0w_wb(
    const float* __restrict__ w, ushort* __restrict__ wb)
{
  const int i = blockIdx.x * 256 + threadIdx.x;
  wb[i] = f2bf(w[i]);
}

// ---------------- K0x: xt[b][n][c] = bf16(x[b][c][n])
__global__ __launch_bounds__(256) void k0x_xt(
    const float* __restrict__ x, ushort* __restrict__ xt)
{
  const int b  = blockIdx.z;
  const int c0 = blockIdx.y * 64;
  const int n0 = blockIdx.x * 64;
  __shared__ ushort tr[64][72];
  const int t = threadIdx.x;
  const float* xb = x + (size_t)b * Dc * NSP;
  const int nl4 = (t & 15) * 4, clb = t >> 4;
#pragma unroll
  for (int r = 0; r < 4; ++r) {
    const int cl = clb + r * 16;
    float4 xv = *(const float4*)(xb + (size_t)(c0 + cl) * NSP + n0 + nl4);
    tr[nl4 + 0][cl] = f2bf(xv.x);
    tr[nl4 + 1][cl] = f2bf(xv.y);
    tr[nl4 + 2][cl] = f2bf(xv.z);
    tr[nl4 + 3][cl] = f2bf(xv.w);
  }
  __syncthreads();
#pragma unroll
  for (int j = 0; j < 2; ++j) {
    const int s  = t + j * 256;
    const int nl = s >> 3, c8 = (s & 7) * 8;
    *(ushort8*)(xt + ((size_t)(b * NSP + n0 + nl)) * Dc + c0 + c8) =
        *(const ushort8*)&tr[nl][c8];
  }
}

// ---------------- K1a: qkt[b][n][o] = bf16(sum_c w[o][c]x[b][c][n] + bias[o]), o<512
__global__ __launch_bounds__(256) void k1a_qk(
    const ushort* __restrict__ wb, const ushort* __restrict__ xt,
    const float* __restrict__ b_qkv, ushort* __restrict__ qkt)
{
  const int b  = blockIdx.z;
  const int m0 = blockIdx.y * 128;   // o
  const int n0 = blockIdx.x * 128;   // n
  f32x4 acc[4][4];
#pragma unroll
  for (int i = 0; i < 4; ++i)
#pragma unroll
    for (int j = 0; j < 4; ++j) acc[i][j] = (f32x4)(0.0f);
  mfma_core<128>(wb, Dc, xt + (size_t)b * NSP * Dc, Dc, m0, n0, Dc, acc);
  const int t = threadIdx.x, lane = t & 63, wid = t >> 6;
  const int wm = (wid >> 1) * 64, wo = (wid & 1) * 64;
  const int lm = lane & 15, lk = lane >> 4;
  ushort* qb = qkt + (size_t)b * NSP * 512;
#pragma unroll
  for (int mi = 0; mi < 4; ++mi) {
    const int o = m0 + wm + mi * 16 + lk * 4;
    float4 bi = *(const float4*)(b_qkv + o);
#pragma unroll
    for (int oi = 0; oi < 4; ++oi) {
      const int n = n0 + wo + oi * 16 + lm;
      f32x4 a = acc[mi][oi];
      ushort4_v st = { f2bf(a.x + bi.x), f2bf(a.y + bi.y),
                       f2bf(a.z + bi.z), f2bf(a.w + bi.w) };
      *(ushort4_v*)(qb + (size_t)n * 512 + o) = st;
    }
  }
}

// ---------------- K1b: vb[b][c][n], BM=64 over n -> 512 blocks
__global__ __launch_bounds__(256) void k1b_v(
    const ushort* __restrict__ wb, const ushort* __restrict__ xt,
    const float* __restrict__ b_qkv, ushort* __restrict__ vb)
{
  const int b  = blockIdx.z;
  const int m0 = blockIdx.y * 64;    // n (16 tiles)
  const int n0 = blockIdx.x * 128;   // c (2 tiles)
  f32x4 acc[2][4];
#pragma unroll
  for (int i = 0; i < 2; ++i)
#pragma unroll
    for (int j = 0; j < 4; ++j) acc[i][j] = (f32x4)(0.0f);
  mfma_core<64>(xt + (size_t)b * NSP * Dc, Dc, wb + 512 * Dc, Dc, m0, n0, Dc, acc);
  const int t = threadIdx.x, lane = t & 63, wid = t >> 6;
  const int wm = (wid >> 1) * 32, wo = (wid & 1) * 64;
  const int lm = lane & 15, lk = lane >> 4;
  ushort* vbb = vb + (size_t)b * Dc * NSP;
#pragma unroll
  for (int oi = 0; oi < 4; ++oi) {
    const int c = n0 + wo + oi * 16 + lm;
    const float bo = b_qkv[512 + c];
#pragma unroll
    for (int mi = 0; mi < 2; ++mi) {
      const int n = m0 + wm + mi * 16 + lk * 4;
      f32x4 a = acc[mi][oi];
      ushort4_v st = { f2bf(a.x + bo), f2bf(a.y + bo),
                       f2bf(a.z + bo), f2bf(a.w + bo) };
      *(ushort4_v*)(vbb + (size_t)c * NSP + n) = st;
    }
  }
}

// ---------------- K2m: S[b][q][k] = 0.0625 * sum_c K[c][k]Q[c][q]  (fp32 out)
__global__ __launch_bounds__(256) void k2m_scores(
    const ushort* __restrict__ qkt, float* __restrict__ S)
{
  const int b  = blockIdx.z;
  const int m0 = blockIdx.y * 128;   // k index
  const int n0 = blockIdx.x * 128;   // q index
  const ushort* base = qkt + (size_t)b * NSP * 512;
  f32x4 acc[4][4];
#pragma unroll
  for (int i = 0; i < 4; ++i)
#pragma unroll
    for (int j = 0; j < 4; ++j) acc[i][j] = (f32x4)(0.0f);
  mfma_core<128>(base + 256, 512, base, 512, m0, n0, Dc, acc);
  const int t = threadIdx.x, lane = t & 63, wid = t >> 6;
  const int wm = (wid >> 1) * 64, wo = (wid & 1) * 64;
  const int lm = lane & 15, lk = lane >> 4;
  float* Sb = S + (size_t)b * NSP * NSP;
#pragma unroll
  for (int oi = 0; oi < 4; ++oi) {
    const int q = n0 + wo + oi * 16 + lm;
#pragma unroll
    for (int mi = 0; mi < 4; ++mi) {
      const int kidx = m0 + wm + mi * 16 + lk * 4;
      f32x4 a = acc[mi][oi] * 0.0625f;
      *(f32x4*)(Sb + (size_t)q * NSP + kidx) = a;
    }
  }
}

// ---------------- K3: row softmax fp32 S -> bf16 P (in place, row-local)
__global__ __launch_bounds__(256) void k3_softmax(
    float* __restrict__ S, ushort* __restrict__ P)
{
  const size_t row = blockIdx.x;
  float* r = S + row * NSP;
  ushort* pr = P + row * 2048;
  const int tid = threadIdx.x;
  float4 v = *(const float4*)(r + (tid << 2));
  float m = fmaxf(fmaxf(v.x, v.y), fmaxf(v.z, v.w));
#pragma unroll
  for (int off = 32; off; off >>= 1) m = fmaxf(m, __shfl_xor(m, off));
  __shared__ float red[4];
  const int wid = tid >> 6, lane = tid & 63;
  if (lane == 0) red[wid] = m;
  __syncthreads();
  m = fmaxf(fmaxf(red[0], red[1]), fmaxf(red[2], red[3]));
  float e0 = __expf(v.x - m), e1 = __expf(v.y - m);
  float e2 = __expf(v.z - m), e3 = __expf(v.w - m);
  float s = e0 + e1 + e2 + e3;
#pragma unroll
  for (int off = 32; off; off >>= 1) s += __shfl_xor(s, off);
  __syncthreads();
  if (lane == 0) red[wid] = s;
  __syncthreads();
  s = red[0] + red[1] + red[2] + red[3];
  const float inv = 1.0f / s;
  ushort4_v st = { f2bf(e0 * inv), f2bf(e1 * inv),
                   f2bf(e2 * inv), f2bf(e3 * inv) };
  *(ushort4_v*)(pr + (tid << 2)) = st;
}

// ---------------- K4m: attn[b][q][c] = sum_k V[c][k] P[q][k], BM=64 over c -> 512 blocks
__global__ __launch_bounds__(256) void k4m_pv(
    const ushort* __restrict__ vb, const ushort* __restrict__ P,
    float* __restrict__ attn)
{
  const int b  = blockIdx.z;
  const int m0 = blockIdx.y * 64;    // c (4 tiles)
  const int n0 = blockIdx.x * 128;   // q (8 tiles)
  f32x4 acc[2][4];
#pragma unroll
  for (int i = 0; i < 2; ++i)
#pragma unroll
    for (int j = 0; j < 4; ++j) acc[i][j] = (f32x4)(0.0f);
  mfma_core<64>(vb + (size_t)b * Dc * NSP, NSP,
                P + (size_t)b * NSP * 2048, 2048, m0, n0, NSP, acc);
  const int t = threadIdx.x, lane = t & 63, wid = t >> 6;
  const int wm = (wid >> 1) * 32, wo = (wid & 1) * 64;
  const int lm = lane & 15, lk = lane >> 4;
  float* ab = attn + (size_t)b * NSP * Dc;
#pragma unroll
  for (int oi = 0; oi < 4; ++oi) {
    const int q = n0 + wo + oi * 16 + lm;
#pragma unroll
    for (int mi = 0; mi < 2; ++mi) {
      const int c = m0 + wm + mi * 16 + lk * 4;
      *(f32x4*)(ab + (size_t)q * Dc + c) = acc[mi][oi];
    }
  }
}

// ---------------- K0wt: w2b[k9][o][ic] = bf16(w_out[o][ic][kh][kw])
__global__ __launch_bounds__(256) void k0_wt(
    const float* __restrict__ w_out, ushort* __restrict__ w2b)
{
  const int o  = blockIdx.x;
  const int ic = threadIdx.x;
  const float* src = w_out + ((size_t)o * Dc + ic) * 9;
#pragma unroll
  for (int k9 = 0; k9 < 9; ++k9)
    w2b[((size_t)k9 * Dc + o) * Dc + ic] = f2bf(src[k9]);
}

// ---------------- K5z: zero the 132 border rows of each batch's padded image
__global__ __launch_bounds__(256) void k5z_border(ushort* __restrict__ x1p)
{
  const int b = blockIdx.x;
  ushort* p = x1p + (size_t)b * 1156 * 256;
  const int t = threadIdx.x;
  for (int r = 0; r < 132; ++r) {
    int r34;
    if (r < 34)      r34 = r;                    // h34 = 0
    else if (r < 68) r34 = 33 * 34 + (r - 34);   // h34 = 33
    else { const int rr = r - 68; r34 = (1 + (rr >> 1)) * 34 + (rr & 1) * 33; }
    p[(size_t)r34 * 256 + t] = 0;
  }
}

// ---------------- K5: x1p[b][(h+1)*34+(w+1)][c] = bf16(x + alpha*relu(attn_flat))
__global__ __launch_bounds__(256) void k5_resid_t(
    const float* __restrict__ x, const float* __restrict__ attn,
    const float* __restrict__ alphap, ushort* __restrict__ x1p)
{
  const int b  = blockIdx.z;
  const int c0 = blockIdx.y * 64;
  const int n0 = blockIdx.x * 64;
  __shared__ ushort tr[64][72];
  const int t = threadIdx.x;
  const float al = *alphap;
  const float* xb = x    + (size_t)b * Dc * NSP;
  const float* ab = attn + (size_t)b * NSP * Dc;   // flat reinterpret
  const int nl4 = (t & 15) * 4, clb = t >> 4;
#pragma unroll
  for (int r = 0; r < 4; ++r) {
    const int cl = clb + r * 16;
    const size_t idx = (size_t)(c0 + cl) * NSP + n0 + nl4;
    float4 xv = *(const float4*)(xb + idx);
    float4 av = *(const float4*)(ab + idx);
    tr[nl4 + 0][cl] = f2bf(xv.x + al * fmaxf(av.x, 0.f));
    tr[nl4 + 1][cl] = f2bf(xv.y + al * fmaxf(av.y, 0.f));
    tr[nl4 + 2][cl] = f2bf(xv.z + al * fmaxf(av.z, 0.f));
    tr[nl4 + 3][cl] = f2bf(xv.w + al * fmaxf(av.w, 0.f));
  }
  __syncthreads();
#pragma unroll
  for (int j = 0; j < 2; ++j) {
    const int s  = t + j * 256;
    const int nl = s >> 3, c8 = (s & 7) * 8;
    const int n  = n0 + nl;
    const int r34 = ((n >> 5) + 1) * 34 + (n & 31) + 1;
    *(ushort8*)(x1p + ((size_t)b * 1156 + r34) * 256 + c0 + c8) =
        *(const ushort8*)&tr[nl][c8];
  }
}

// ---------------- K6: out = x1 + alpha*relu(conv3x3(x1)+b_out)
// MFMA implicit GEMM on padded image; distance-3 prefetch, triple-buffer LDS,
// non-draining barriers (loads stay in flight).
__global__ __launch_bounds__(256) void k6_conv_mfma(
    const float* __restrict__ x, const float* __restrict__ attn,
    const ushort* __restrict__ x1p, const ushort* __restrict__ w2b,
    const float* __restrict__ bout, const float* __restrict__ alphap,
    float* __restrict__ out)
{
  const int b  = blockIdx.z;
  const int n0 = blockIdx.x * 128;
  const int o0 = blockIdx.y * 128;
  __shared__ short As[3][128 * 32];
  __shared__ short Ws[3][128 * 32];
  const int t = threadIdx.x;
  const int lane = t & 63, wid = t >> 6;
  const int wm = (wid >> 1) * 64, wo = (wid & 1) * 64;
  const int lm = lane & 15, lk = lane >> 4;
  const int aph = lk ^ ((lm >> 1) & 3);

  const int row0 = t >> 2, chunk = t & 3;
  const int phys = chunk ^ ((row0 >> 1) & 3);
  const int st0 = row0 * 32 + phys * 8;
  const int n_r0 = n0 + row0;
  const int n_r1 = n_r0 + 64;
  const int r34_0 = ((n_r0 >> 5) + 1) * 34 + (n_r0 & 31) + 1;
  const int r34_1 = ((n_r1 >> 5) + 1) * 34 + (n_r1 & 31) + 1;

  const ushort* xp = x1p + (size_t)b * 1156 * 256;

  auto ldA = [&](int kn, int slot) -> short8 {
    const int k9 = kn >> 3, c0 = (kn & 7) << 5;
    const int dh = ((k9 * 11) >> 5) - 1;
    const int dw = k9 - (dh + 1) * 3 - 1;
    const int r34 = (slot ? r34_1 : r34_0) + dh * 34 + dw;
    return *(const short8*)(xp + (size_t)r34 * 256 + c0 + chunk * 8);
  };
  auto ldW = [&](int kn, int slot) -> short8 {
    const int k9 = kn >> 3, c0 = (kn & 7) << 5;
    return *(const short8*)(w2b +
        ((size_t)k9 * Dc + o0 + row0 + slot * 64) * Dc + c0 + chunk * 8);
  };

  f32x4 acc[4][4];
#pragma unroll
  for (int i = 0; i < 4; ++i)
#pragma unroll
    for (int j = 0; j < 4; ++j) acc[i][j] = (f32x4)(0.0f);

  short8 a00 = ldA(0, 0), a01 = ldA(0, 1), q00 = ldW(0, 0), q01 = ldW(0, 1);
  short8 a10 = ldA(1, 0), a11 = ldA(1, 1), q10 = ldW(1, 0), q11 = ldW(1, 1);
  short8 a20 = ldA(2, 0), a21 = ldA(2, 1), q20 = ldW(2, 0), q21 = ldW(2, 1);

  auto stepK = [&](int kk, short* Ab, short* Wb,
                   short8& ra0, short8& ra1, short8& rq0, short8& rq1) {
    *(short8*)&Ab[st0] = ra0;  *(short8*)&Ab[st0 + 2048] = ra1;
    *(short8*)&Wb[st0] = rq0;  *(short8*)&Wb[st0 + 2048] = rq1;
    if (kk + 3 < 72) {
      ra0 = ldA(kk + 3, 0);  ra1 = ldA(kk + 3, 1);
      rq0 = ldW(kk + 3, 0);  rq1 = ldW(kk + 3, 1);
    }
    sync_lds();
    short8 af[4], bw[4];
#pragma unroll
    for (int mi = 0; mi < 4; ++mi)
      af[mi] = *(const short8*)&Ab[(wm + mi * 16 + lm) * 32 + aph * 8];
#pragma unroll
    for (int oi = 0; oi < 4; ++oi)
      bw[oi] = *(const short8*)&Wb[(wo + oi * 16 + lm) * 32 + aph * 8];
#pragma unroll
    for (int mi = 0; mi < 4; ++mi)
#pragma unroll
      for (int oi = 0; oi < 4; ++oi)
        acc[mi][oi] = __builtin_amdgcn_mfma_f32_16x16x32_bf16(
            af[mi], bw[oi], acc[mi][oi], 0, 0, 0);
  };

  for (int kk = 0; kk < 72; kk += 3) {
    stepK(kk,     &As[0][0], &Ws[0][0], a00, a01, q00, q01);
    stepK(kk + 1, &As[1][0], &Ws[1][0], a10, a11, q10, q11);
    stepK(kk + 2, &As[2][0], &Ws[2][0], a20, a21, q20, q21);
  }

  const float al = *alphap;
  const float* xb32 = x    + (size_t)b * Dc * NSP;
  const float* at32 = attn + (size_t)b * NSP * Dc;
  float* ob = out + (size_t)b * Dc * NSP;
#pragma unroll
  for (int oi = 0; oi < 4; ++oi) {
    const int o = o0 + wo + oi * 16 + lm;
    const float bo = bout[o];
#pragma unroll
    for (int mi = 0; mi < 4; ++mi) {
      const int nr = n0 + wm + mi * 16 + lk * 4;
      const size_t idx = (size_t)o * NSP + nr;
      float4 xv = *(const float4*)(xb32 + idx);
      float4 av = *(const float4*)(at32 + idx);
      f32x4 a = acc[mi][oi];
      float4 r;
      r.x = xv.x + al * fmaxf(av.x, 0.f) + al * fmaxf(a.x + bo, 0.f);
      r.y = xv.y + al * fmaxf(av.y, 0.f) + al * fmaxf(a.y + bo, 0.f);
      r.z = xv.z + al * fmaxf(av.z, 0.f) + al * fmaxf(a.z + bo, 0.f);
      r.w = xv.w + al * fmaxf(av.w, 0.f) + al * fmaxf(a.w + bo, 0.f);
      *(float4*)(ob + idx) = r;
    }
  }
}

}  // namespace

extern "C" void kernel_launch(void* const* d_in, const int* in_sizes, int n_in,
                              void* d_out, int out_size, void* d_ws, size_t ws_size,
                              hipStream_t stream)
{
  const float* x     = (const float*)d_in[0];
  const float* w_qkv = (const float*)d_in[1];
  const float* b_qkv = (const float*)d_in[2];
  const float* w_out = (const float*)d_in[3];
  const float* b_out = (const float*)d_in[4];
  const float* alpha = (const float*)d_in[5];
  float* out = (float*)d_out;

  // Workspace layout (byte offsets), total 96.5 MB:
  //   [0,16M)       qkt bf16 [b][n][512]  -> dead after k2m -> attn fp32 [b][q][c]
  //   [16M,24M)     vb  bf16 [b][c][n]    (dead after k4m)
  //   [24M,32M)     xt  bf16 [b][n][c]    -> dead after k1b -> w2b bf16 [9][o][ic]
  //   [32M,32.5M)   wb  bf16 [768][256]
  //   [32.5M,96.5M) S fp32 [b][q][k] -> P bf16 in-place (stride 2048 ush)
  //                 -> dead after k4m -> x1p bf16 [b][34*34][256] (9.5 MB)
  char* ws = (char*)d_ws;
  ushort* qkt  = (ushort*)ws;
  float*  attn = (float*)ws;
  ushort* vb   = (ushort*)(ws + (16u << 20));
  ushort* xt   = (ushort*)(ws + (24u << 20));
  ushort* w2b  = xt;
  ushort* wb   = (ushort*)(ws + (32u << 20));
  float*  S    = (float*)(ws + (32u << 20) + (1u << 19));
  ushort* Pus  = (ushort*)S;
  ushort* x1p  = (ushort*)S;

  k0w_wb      <<<dim3(768),        256, 0, stream>>>(w_qkv, wb);
  k0x_xt      <<<dim3(16, 4, 16),  256, 0, stream>>>(x, xt);
  k1a_qk      <<<dim3(8, 4, 16),   256, 0, stream>>>(wb, xt, b_qkv, qkt);
  k1b_v       <<<dim3(2, 16, 16),  256, 0, stream>>>(wb, xt, b_qkv, vb);
  k0_wt       <<<dim3(256),        256, 0, stream>>>(w_out, w2b);
  k2m_scores  <<<dim3(8, 8, 16),   256, 0, stream>>>(qkt, S);
  k3_softmax  <<<dim3(16384),      256, 0, stream>>>(S, Pus);
  k4m_pv      <<<dim3(8, 4, 16),   256, 0, stream>>>(vb, Pus, attn);
  k5z_border  <<<dim3(16),         256, 0, stream>>>(x1p);
  k5_resid_t  <<<dim3(16, 4, 16),  256, 0, stream>>>(x, attn, alpha, x1p);
  k6_conv_mfma<<<dim3(8, 2, 16),   256, 0, stream>>>(x, attn, x1p, w2b, b_out, alpha, out);
}

// Round 6
// 149.302 us; speedup vs baseline: 1.0142x; 1.0142x over previous
//
#include <hip/hip_runtime.h>
#include <cmath>

namespace {

constexpr int Dc  = 256;    // channels
constexpr int NB  = 16;     // batch
constexpr int NSP = 1024;   // H*W
constexpr int OC3 = 768;    // 3*D

typedef __attribute__((ext_vector_type(8))) short  short8;
typedef __attribute__((ext_vector_type(8))) ushort ushort8;
typedef __attribute__((ext_vector_type(4))) ushort ushort4_v;
typedef __attribute__((ext_vector_type(4))) float  f32x4;

__device__ inline ushort f2bf(float f) {
  unsigned u = __builtin_bit_cast(unsigned, f);
  unsigned r = (u + 0x7FFFu + ((u >> 16) & 1u)) >> 16;
  return (ushort)r;
}

// Barrier without the compiler's vmcnt(0) drain (prefetch loads stay in
// flight across the barrier). lgkmcnt(0) publishes our LDS writes and
// retires our LDS reads before the rendezvous.
__device__ __forceinline__ void sync_lds() {
  __builtin_amdgcn_sched_barrier(0);
  asm volatile("s_waitcnt lgkmcnt(0)" ::: "memory");
  __builtin_amdgcn_s_barrier();
  __builtin_amdgcn_sched_barrier(0);
}

// ---------------- templated MFMA GEMM core (bf16, fp32 acc) ----------------
// C[m][n] = sum_k A[m0+m][k]*B[n0+n][k]; tile BM x 128, 4 waves, BK=32,
// distance-2 register prefetch (static reg sets), double-buffered LDS,
// XOR chunk swizzle (bank-conflict free, verified r2: SQ_LDS_BANK_CONFLICT=0).
// REQUIRES: (K/32) even.
template<int BM>
__device__ __forceinline__ void mfma_core(
    const ushort* __restrict__ Abase, int lda,
    const ushort* __restrict__ Bbase, int ldb,
    int m0, int n0, int K, f32x4 (&acc)[BM / 32][4])
{
  constexpr int MI  = BM / 32;   // m-frags per wave
  constexpr int ASL = BM / 64;   // A staging slots per thread
  __shared__ short As[2][BM * 32];
  __shared__ short Bs[2][128 * 32];
  const int t = threadIdx.x;
  const int lane = t & 63, wid = t >> 6;
  const int wm = (wid >> 1) * (BM / 2);
  const int wo = (wid & 1) * 64;
  const int lm = lane & 15, lk = lane >> 4;
  const int aph = lk ^ ((lm >> 1) & 3);

  const int row0 = t >> 2, chunk = t & 3;
  const int phys = chunk ^ ((row0 >> 1) & 3);
  const int st0 = row0 * 32 + phys * 8;

  const ushort* Ap = Abase + (size_t)(m0 + row0) * lda + chunk * 8;
  const ushort* Bp = Bbase + (size_t)(n0 + row0) * ldb + chunk * 8;
  const size_t lda64 = (size_t)64 * lda;
  const size_t ldb64 = (size_t)64 * ldb;
  const int niter = K >> 5;

  short8 a0[ASL], a1[ASL], b0[2], b1[2];
#pragma unroll
  for (int i = 0; i < ASL; ++i) {
    a0[i] = *(const short8*)(Ap + i * lda64);
    a1[i] = *(const short8*)(Ap + i * lda64 + 32);
  }
  b0[0] = *(const short8*)(Bp);
  b0[1] = *(const short8*)(Bp + ldb64);
  b1[0] = *(const short8*)(Bp + 32);
  b1[1] = *(const short8*)(Bp + ldb64 + 32);

  auto step = [&](int kk, int buf, short8 (&ar)[ASL], short8 (&br)[2]) {
    short* Ab = &As[buf][0];
    short* Bb = &Bs[buf][0];
#pragma unroll
    for (int i = 0; i < ASL; ++i) *(short8*)&Ab[st0 + i * 2048] = ar[i];
    *(short8*)&Bb[st0] = br[0];
    *(short8*)&Bb[st0 + 2048] = br[1];
    if (kk + 2 < niter) {
      const int c0 = (kk + 2) << 5;
#pragma unroll
      for (int i = 0; i < ASL; ++i)
        ar[i] = *(const short8*)(Ap + i * lda64 + c0);
      br[0] = *(const short8*)(Bp + c0);
      br[1] = *(const short8*)(Bp + ldb64 + c0);
    }
    sync_lds();
    short8 af[MI], bw[4];
#pragma unroll
    for (int mi = 0; mi < MI; ++mi)
      af[mi] = *(const short8*)&Ab[(wm + mi * 16 + lm) * 32 + aph * 8];
#pragma unroll
    for (int oi = 0; oi < 4; ++oi)
      bw[oi] = *(const short8*)&Bb[(wo + oi * 16 + lm) * 32 + aph * 8];
#pragma unroll
    for (int mi = 0; mi < MI; ++mi)
#pragma unroll
      for (int oi = 0; oi < 4; ++oi)
        acc[mi][oi] = __builtin_amdgcn_mfma_f32_16x16x32_bf16(
            af[mi], bw[oi], acc[mi][oi], 0, 0, 0);
  };

  for (int kk = 0; kk < niter; kk += 2) {
    step(kk, 0, a0, b0);
    step(kk + 1, 1, a1, b1);
  }
}

// ---------------- K0w: wb[o][c] = bf16(w_qkv[o][c])
__global__ __launch_bounds__(256) void k0w_wb(
    const float* __restrict__ w, ushort* __restrict__ wb)
{
  const int i = blockIdx.x * 256 + threadIdx.x;
  wb[i] = f2bf(w[i]);
}

// ---------------- K0x: xt[b][n][c] = bf16(x[b][c][n])
__global__ __launch_bounds__(256) void k0x_xt(
    const float* __restrict__ x, ushort* __restrict__ xt)
{
  const int b  = blockIdx.z;
  const int c0 = blockIdx.y * 64;
  const int n0 = blockIdx.x * 64;
  __shared__ ushort tr[64][72];
  const int t = threadIdx.x;
  const float* xb = x + (size_t)b * Dc * NSP;
  const int nl4 = (t & 15) * 4, clb = t >> 4;
#pragma unroll
  for (int r = 0; r < 4; ++r) {
    const int cl = clb + r * 16;
    float4 xv = *(const float4*)(xb + (size_t)(c0 + cl) * NSP + n0 + nl4);
    tr[nl4 + 0][cl] = f2bf(xv.x);
    tr[nl4 + 1][cl] = f2bf(xv.y);
    tr[nl4 + 2][cl] = f2bf(xv.z);
    tr[nl4 + 3][cl] = f2bf(xv.w);
  }
  __syncthreads();
#pragma unroll
  for (int j = 0; j < 2; ++j) {
    const int s  = t + j * 256;
    const int nl = s >> 3, c8 = (s & 7) * 8;
    *(ushort8*)(xt + ((size_t)(b * NSP + n0 + nl)) * Dc + c0 + c8) =
        *(const ushort8*)&tr[nl][c8];
  }
}

// ---------------- K1a: qkt[b][n][o] = bf16(sum_c w[o][c]x[b][c][n] + bias[o]), o<512
__global__ __launch_bounds__(256) void k1a_qk(
    const ushort* __restrict__ wb, const ushort* __restrict__ xt,
    const float* __restrict__ b_qkv, ushort* __restrict__ qkt)
{
  const int b  = blockIdx.z;
  const int m0 = blockIdx.y * 128;   // o
  const int n0 = blockIdx.x * 128;   // n
  f32x4 acc[4][4];
#pragma unroll
  for (int i = 0; i < 4; ++i)
#pragma unroll
    for (int j = 0; j < 4; ++j) acc[i][j] = (f32x4)(0.0f);
  mfma_core<128>(wb, Dc, xt + (size_t)b * NSP * Dc, Dc, m0, n0, Dc, acc);
  const int t = threadIdx.x, lane = t & 63, wid = t >> 6;
  const int wm = (wid >> 1) * 64, wo = (wid & 1) * 64;
  const int lm = lane & 15, lk = lane >> 4;
  ushort* qb = qkt + (size_t)b * NSP * 512;
#pragma unroll
  for (int mi = 0; mi < 4; ++mi) {
    const int o = m0 + wm + mi * 16 + lk * 4;
    float4 bi = *(const float4*)(b_qkv + o);
#pragma unroll
    for (int oi = 0; oi < 4; ++oi) {
      const int n = n0 + wo + oi * 16 + lm;
      f32x4 a = acc[mi][oi];
      ushort4_v st = { f2bf(a.x + bi.x), f2bf(a.y + bi.y),
                       f2bf(a.z + bi.z), f2bf(a.w + bi.w) };
      *(ushort4_v*)(qb + (size_t)n * 512 + o) = st;
    }
  }
}

// ---------------- K1b: vb[b][c][n], BM=64 over n -> 512 blocks
__global__ __launch_bounds__(256) void k1b_v(
    const ushort* __restrict__ wb, const ushort* __restrict__ xt,
    const float* __restrict__ b_qkv, ushort* __restrict__ vb)
{
  const int b  = blockIdx.z;
  const int m0 = blockIdx.y * 64;    // n (16 tiles)
  const int n0 = blockIdx.x * 128;   // c (2 tiles)
  f32x4 acc[2][4];
#pragma unroll
  for (int i = 0; i < 2; ++i)
#pragma unroll
    for (int j = 0; j < 4; ++j) acc[i][j] = (f32x4)(0.0f);
  mfma_core<64>(xt + (size_t)b * NSP * Dc, Dc, wb + 512 * Dc, Dc, m0, n0, Dc, acc);
  const int t = threadIdx.x, lane = t & 63, wid = t >> 6;
  const int wm = (wid >> 1) * 32, wo = (wid & 1) * 64;
  const int lm = lane & 15, lk = lane >> 4;
  ushort* vbb = vb + (size_t)b * Dc * NSP;
#pragma unroll
  for (int oi = 0; oi < 4; ++oi) {
    const int c = n0 + wo + oi * 16 + lm;
    const float bo = b_qkv[512 + c];
#pragma unroll
    for (int mi = 0; mi < 2; ++mi) {
      const int n = m0 + wm + mi * 16 + lk * 4;
      f32x4 a = acc[mi][oi];
      ushort4_v st = { f2bf(a.x + bo), f2bf(a.y + bo),
                       f2bf(a.z + bo), f2bf(a.w + bo) };
      *(ushort4_v*)(vbb + (size_t)c * NSP + n) = st;
    }
  }
}

// ---------------- K2m: S[b][q][k] = 0.0625 * sum_c K[c][k]Q[c][q]  (fp32 out)
__global__ __launch_bounds__(256) void k2m_scores(
    const ushort* __restrict__ qkt, float* __restrict__ S)
{
  const int b  = blockIdx.z;
  const int m0 = blockIdx.y * 128;   // k index
  const int n0 = blockIdx.x * 128;   // q index
  const ushort* base = qkt + (size_t)b * NSP * 512;
  f32x4 acc[4][4];
#pragma unroll
  for (int i = 0; i < 4; ++i)
#pragma unroll
    for (int j = 0; j < 4; ++j) acc[i][j] = (f32x4)(0.0f);
  mfma_core<128>(base + 256, 512, base, 512, m0, n0, Dc, acc);
  const int t = threadIdx.x, lane = t & 63, wid = t >> 6;
  const int wm = (wid >> 1) * 64, wo = (wid & 1) * 64;
  const int lm = lane & 15, lk = lane >> 4;
  float* Sb = S + (size_t)b * NSP * NSP;
#pragma unroll
  for (int oi = 0; oi < 4; ++oi) {
    const int q = n0 + wo + oi * 16 + lm;
#pragma unroll
    for (int mi = 0; mi < 4; ++mi) {
      const int kidx = m0 + wm + mi * 16 + lk * 4;
      f32x4 a = acc[mi][oi] * 0.0625f;
      *(f32x4*)(Sb + (size_t)q * NSP + kidx) = a;
    }
  }
}

// ---------------- K3: row softmax fp32 S -> bf16 P (in place, row-local)
__global__ __launch_bounds__(256) void k3_softmax(
    float* __restrict__ S, ushort* __restrict__ P)
{
  const size_t row = blockIdx.x;
  float* r = S + row * NSP;
  ushort* pr = P + row * 2048;
  const int tid = threadIdx.x;
  float4 v = *(const float4*)(r + (tid << 2));
  float m = fmaxf(fmaxf(v.x, v.y), fmaxf(v.z, v.w));
#pragma unroll
  for (int off = 32; off; off >>= 1) m = fmaxf(m, __shfl_xor(m, off));
  __shared__ float red[4];
  const int wid = tid >> 6, lane = tid & 63;
  if (lane == 0) red[wid] = m;
  __syncthreads();
  m = fmaxf(fmaxf(red[0], red[1]), fmaxf(red[2], red[3]));
  float e0 = __expf(v.x - m), e1 = __expf(v.y - m);
  float e2 = __expf(v.z - m), e3 = __expf(v.w - m);
  float s = e0 + e1 + e2 + e3;
#pragma unroll
  for (int off = 32; off; off >>= 1) s += __shfl_xor(s, off);
  __syncthreads();
  if (lane == 0) red[wid] = s;
  __syncthreads();
  s = red[0] + red[1] + red[2] + red[3];
  const float inv = 1.0f / s;
  ushort4_v st = { f2bf(e0 * inv), f2bf(e1 * inv),
                   f2bf(e2 * inv), f2bf(e3 * inv) };
  *(ushort4_v*)(pr + (tid << 2)) = st;
}

// ---------------- K4m: attn[b][q][c] = sum_k V[c][k] P[q][k], BM=64 over c -> 512 blocks
__global__ __launch_bounds__(256) void k4m_pv(
    const ushort* __restrict__ vb, const ushort* __restrict__ P,
    float* __restrict__ attn)
{
  const int b  = blockIdx.z;
  const int m0 = blockIdx.y * 64;    // c (4 tiles)
  const int n0 = blockIdx.x * 128;   // q (8 tiles)
  f32x4 acc[2][4];
#pragma unroll
  for (int i = 0; i < 2; ++i)
#pragma unroll
    for (int j = 0; j < 4; ++j) acc[i][j] = (f32x4)(0.0f);
  mfma_core<64>(vb + (size_t)b * Dc * NSP, NSP,
                P + (size_t)b * NSP * 2048, 2048, m0, n0, NSP, acc);
  const int t = threadIdx.x, lane = t & 63, wid = t >> 6;
  const int wm = (wid >> 1) * 32, wo = (wid & 1) * 64;
  const int lm = lane & 15, lk = lane >> 4;
  float* ab = attn + (size_t)b * NSP * Dc;
#pragma unroll
  for (int oi = 0; oi < 4; ++oi) {
    const int q = n0 + wo + oi * 16 + lm;
#pragma unroll
    for (int mi = 0; mi < 2; ++mi) {
      const int c = m0 + wm + mi * 16 + lk * 4;
      *(f32x4*)(ab + (size_t)q * Dc + c) = acc[mi][oi];
    }
  }
}

// ---------------- K0wt: w2b[k9][o][ic] = bf16(w_out[o][ic][kh][kw])
__global__ __launch_bounds__(256) void k0_wt(
    const float* __restrict__ w_out, ushort* __restrict__ w2b)
{
  const int o  = blockIdx.x;
  const int ic = threadIdx.x;
  const float* src = w_out + ((size_t)o * Dc + ic) * 9;
#pragma unroll
  for (int k9 = 0; k9 < 9; ++k9)
    w2b[((size_t)k9 * Dc + o) * Dc + ic] = f2bf(src[k9]);
}

// ---------------- K5z: zero the 132 border rows of each batch's padded image
__global__ __launch_bounds__(256) void k5z_border(ushort* __restrict__ x1p)
{
  const int b = blockIdx.x;
  ushort* p = x1p + (size_t)b * 1156 * 256;
  const int t = threadIdx.x;
  for (int r = 0; r < 132; ++r) {
    int r34;
    if (r < 34)      r34 = r;                    // h34 = 0
    else if (r < 68) r34 = 33 * 34 + (r - 34);   // h34 = 33
    else { const int rr = r - 68; r34 = (1 + (rr >> 1)) * 34 + (rr & 1) * 33; }
    p[(size_t)r34 * 256 + t] = 0;
  }
}

// ---------------- K5: x1p[b][(h+1)*34+(w+1)][c] = bf16(x + alpha*relu(attn_flat))
__global__ __launch_bounds__(256) void k5_resid_t(
    const float* __restrict__ x, const float* __restrict__ attn,
    const float* __restrict__ alphap, ushort* __restrict__ x1p)
{
  const int b  = blockIdx.z;
  const int c0 = blockIdx.y * 64;
  const int n0 = blockIdx.x * 64;
  __shared__ ushort tr[64][72];
  const int t = threadIdx.x;
  const float al = *alphap;
  const float* xb = x    + (size_t)b * Dc * NSP;
  const float* ab = attn + (size_t)b * NSP * Dc;   // flat reinterpret
  const int nl4 = (t & 15) * 4, clb = t >> 4;
#pragma unroll
  for (int r = 0; r < 4; ++r) {
    const int cl = clb + r * 16;
    const size_t idx = (size_t)(c0 + cl) * NSP + n0 + nl4;
    float4 xv = *(const float4*)(xb + idx);
    float4 av = *(const float4*)(ab + idx);
    tr[nl4 + 0][cl] = f2bf(xv.x + al * fmaxf(av.x, 0.f));
    tr[nl4 + 1][cl] = f2bf(xv.y + al * fmaxf(av.y, 0.f));
    tr[nl4 + 2][cl] = f2bf(xv.z + al * fmaxf(av.z, 0.f));
    tr[nl4 + 3][cl] = f2bf(xv.w + al * fmaxf(av.w, 0.f));
  }
  __syncthreads();
#pragma unroll
  for (int j = 0; j < 2; ++j) {
    const int s  = t + j * 256;
    const int nl = s >> 3, c8 = (s & 7) * 8;
    const int n  = n0 + nl;
    const int r34 = ((n >> 5) + 1) * 34 + (n & 31) + 1;
    *(ushort8*)(x1p + ((size_t)b * 1156 + r34) * 256 + c0 + c8) =
        *(const ushort8*)&tr[nl][c8];
  }
}

// ---------------- K6: out = x1 + alpha*relu(conv3x3(x1)+b_out)
// MFMA implicit GEMM, BM=64(n) x BN=128(o) -> 512 blocks (2 blocks/CU for TLP),
// double-buffered LDS, distance-2 prefetch, non-draining barriers.
__global__ __launch_bounds__(256) void k6_conv_mfma(
    const float* __restrict__ x, const float* __restrict__ attn,
    const ushort* __restrict__ x1p, const ushort* __restrict__ w2b,
    const float* __restrict__ bout, const float* __restrict__ alphap,
    float* __restrict__ out)
{
  const int b  = blockIdx.z;
  const int n0 = blockIdx.x * 64;    // 16 n-tiles
  const int o0 = blockIdx.y * 128;   // 2 o-tiles
  __shared__ short As[2][64 * 32];
  __shared__ short Ws[2][128 * 32];
  const int t = threadIdx.x;
  const int lane = t & 63, wid = t >> 6;
  const int wm = (wid >> 1) * 32, wo = (wid & 1) * 64;
  const int lm = lane & 15, lk = lane >> 4;
  const int aph = lk ^ ((lm >> 1) & 3);

  const int row0 = t >> 2, chunk = t & 3;
  const int phys = chunk ^ ((row0 >> 1) & 3);
  const int st0 = row0 * 32 + phys * 8;
  const int n_r0 = n0 + row0;
  const int r34_0 = ((n_r0 >> 5) + 1) * 34 + (n_r0 & 31) + 1;

  const ushort* xp = x1p + (size_t)b * 1156 * 256;

  auto ldA = [&](int kn) -> short8 {
    const int k9 = kn >> 3, c0 = (kn & 7) << 5;
    const int dh = ((k9 * 11) >> 5) - 1;
    const int dw = k9 - (dh + 1) * 3 - 1;
    return *(const short8*)(xp + (size_t)(r34_0 + dh * 34 + dw) * 256 +
                            c0 + chunk * 8);
  };
  auto ldW = [&](int kn, int slot) -> short8 {
    const int k9 = kn >> 3, c0 = (kn & 7) << 5;
    return *(const short8*)(w2b +
        ((size_t)k9 * Dc + o0 + row0 + slot * 64) * Dc + c0 + chunk * 8);
  };

  f32x4 acc[2][4];
#pragma unroll
  for (int i = 0; i < 2; ++i)
#pragma unroll
    for (int j = 0; j < 4; ++j) acc[i][j] = (f32x4)(0.0f);

  short8 a0 = ldA(0), q00 = ldW(0, 0), q01 = ldW(0, 1);
  short8 a1 = ldA(1), q10 = ldW(1, 0), q11 = ldW(1, 1);

  auto stepK = [&](int kk, int buf, short8& ra, short8& rq0, short8& rq1) {
    short* Ab = &As[buf][0];
    short* Wb = &Ws[buf][0];
    *(short8*)&Ab[st0] = ra;
    *(short8*)&Wb[st0] = rq0;  *(short8*)&Wb[st0 + 2048] = rq1;
    if (kk + 2 < 72) {
      ra  = ldA(kk + 2);
      rq0 = ldW(kk + 2, 0);
      rq1 = ldW(kk + 2, 1);
    }
    sync_lds();
    short8 af[2], bw[4];
#pragma unroll
    for (int mi = 0; mi < 2; ++mi)
      af[mi] = *(const short8*)&Ab[(wm + mi * 16 + lm) * 32 + aph * 8];
#pragma unroll
    for (int oi = 0; oi < 4; ++oi)
      bw[oi] = *(const short8*)&Wb[(wo + oi * 16 + lm) * 32 + aph * 8];
#pragma unroll
    for (int mi = 0; mi < 2; ++mi)
#pragma unroll
      for (int oi = 0; oi < 4; ++oi)
        acc[mi][oi] = __builtin_amdgcn_mfma_f32_16x16x32_bf16(
            af[mi], bw[oi], acc[mi][oi], 0, 0, 0);
  };

  for (int kk = 0; kk < 72; kk += 2) {
    stepK(kk,     0, a0, q00, q01);
    stepK(kk + 1, 1, a1, q10, q11);
  }

  const float al = *alphap;
  const float* xb32 = x    + (size_t)b * Dc * NSP;
  const float* at32 = attn + (size_t)b * NSP * Dc;
  float* ob = out + (size_t)b * Dc * NSP;
#pragma unroll
  for (int oi = 0; oi < 4; ++oi) {
    const int o = o0 + wo + oi * 16 + lm;
    const float bo = bout[o];
#pragma unroll
    for (int mi = 0; mi < 2; ++mi) {
      const int nr = n0 + wm + mi * 16 + lk * 4;
      const size_t idx = (size_t)o * NSP + nr;
      float4 xv = *(const float4*)(xb32 + idx);
      float4 av = *(const float4*)(at32 + idx);
      f32x4 a = acc[mi][oi];
      float4 r;
      r.x = xv.x + al * fmaxf(av.x, 0.f) + al * fmaxf(a.x + bo, 0.f);
      r.y = xv.y + al * fmaxf(av.y, 0.f) + al * fmaxf(a.y + bo, 0.f);
      r.z = xv.z + al * fmaxf(av.z, 0.f) + al * fmaxf(a.z + bo, 0.f);
      r.w = xv.w + al * fmaxf(av.w, 0.f) + al * fmaxf(a.w + bo, 0.f);
      *(float4*)(ob + idx) = r;
    }
  }
}

}  // namespace

extern "C" void kernel_launch(void* const* d_in, const int* in_sizes, int n_in,
                              void* d_out, int out_size, void* d_ws, size_t ws_size,
                              hipStream_t stream)
{
  const float* x     = (const float*)d_in[0];
  const float* w_qkv = (const float*)d_in[1];
  const float* b_qkv = (const float*)d_in[2];
  const float* w_out = (const float*)d_in[3];
  const float* b_out = (const float*)d_in[4];
  const float* alpha = (const float*)d_in[5];
  float* out = (float*)d_out;

  // Workspace layout (byte offsets), total 96.5 MB:
  //   [0,16M)       qkt bf16 [b][n][512]  -> dead after k2m -> attn fp32 [b][q][c]
  //   [16M,24M)     vb  bf16 [b][c][n]    (dead after k4m)
  //   [24M,32M)     xt  bf16 [b][n][c]    -> dead after k1b -> w2b bf16 [9][o][ic]
  //   [32M,32.5M)   wb  bf16 [768][256]
  //   [32.5M,96.5M) S fp32 [b][q][k] -> P bf16 in-place (stride 2048 ush)
  //                 -> dead after k4m -> x1p bf16 [b][34*34][256] (9.5 MB)
  char* ws = (char*)d_ws;
  ushort* qkt  = (ushort*)ws;
  float*  attn = (float*)ws;
  ushort* vb   = (ushort*)(ws + (16u << 20));
  ushort* xt   = (ushort*)(ws + (24u << 20));
  ushort* w2b  = xt;
  ushort* wb   = (ushort*)(ws + (32u << 20));
  float*  S    = (float*)(ws + (32u << 20) + (1u << 19));
  ushort* Pus  = (ushort*)S;
  ushort* x1p  = (ushort*)S;

  k0w_wb      <<<dim3(768),        256, 0, stream>>>(w_qkv, wb);
  k0x_xt      <<<dim3(16, 4, 16),  256, 0, stream>>>(x, xt);
  k1a_qk      <<<dim3(8, 4, 16),   256, 0, stream>>>(wb, xt, b_qkv, qkt);
  k1b_v       <<<dim3(2, 16, 16),  256, 0, stream>>>(wb, xt, b_qkv, vb);
  k0_wt       <<<dim3(256),        256, 0, stream>>>(w_out, w2b);
  k2m_scores  <<<dim3(8, 8, 16),   256, 0, stream>>>(qkt, S);
  k3_softmax  <<<dim3(16384),      256, 0, stream>>>(S, Pus);
  k4m_pv      <<<dim3(8, 4, 16),   256, 0, stream>>>(vb, Pus, attn);
  k5z_border  <<<dim3(16),         256, 0, stream>>>(x1p);
  k5_resid_t  <<<dim3(16, 4, 16),  256, 0, stream>>>(x, attn, alpha, x1p);
  k6_conv_mfma<<<dim3(16, 2, 16),  256, 0, stream>>>(x, attn, x1p, w2b, b_out, alpha, out);
}